// Round 2
// baseline (921.297 us; speedup 1.0000x reference)
//
#include <hip/hip_runtime.h>
#include <hip/hip_bf16.h>
#include <cstdint>

#define L_SEQ 1024
#define BSZ   16
#define DIN   2048
#define DD    2048
#define MROWS (L_SEQ * BSZ)   // 16384
#define NCOLS (3 * DD)        // 6144
#define BK    32

typedef __attribute__((ext_vector_type(8))) short  short8;
typedef __attribute__((ext_vector_type(4))) float  f32x4;
typedef __attribute__((ext_vector_type(4))) ushort ushort4v;

typedef const __attribute__((address_space(1))) void* gas_ptr;
typedef __attribute__((address_space(3))) void*       las_ptr;

#define GLOAD16(g, l) __builtin_amdgcn_global_load_lds((gas_ptr)(g), (las_ptr)(l), 16, 0, 0)

__device__ __forceinline__ float bf2f(ushort u) {
    return __uint_as_float(((uint32_t)u) << 16);
}
__device__ __forceinline__ ushort f2bf(float f) {
    uint32_t u = __float_as_uint(f);
    uint32_t r = u + 0x7FFFu + ((u >> 16) & 1u);  // RNE
    return (ushort)(r >> 16);
}

// ---------------- K0a: x f32 -> bf16 ----------------
__global__ __launch_bounds__(256) void cvt_x_kernel(const f32x4* __restrict__ x,
                                                    ushort4v* __restrict__ xb, int n4) {
    int i = blockIdx.x * blockDim.x + threadIdx.x;
    int stride = gridDim.x * blockDim.x;
    for (; i < n4; i += stride) {
        f32x4 v = x[i];
        ushort4v o;
        o.x = f2bf(v.x); o.y = f2bf(v.y); o.z = f2bf(v.z); o.w = f2bf(v.w);
        xb[i] = o;
    }
}

// ---------------- K0b: W [DIN][NCOLS] f32 -> WT bf16, channel-deinterleaved ----------------
// Source column n maps to (dd = n/3, kk = n%3); we store it at row n' = kk*DD + dd of WT
// so the GEMM output is planar: cols [0,2048) = u0, [2048,4096) = g1, [4096,6144) = g2.
__global__ __launch_bounds__(256) void transpose_w_kernel(const float* __restrict__ W,
                                                          ushort* __restrict__ WT) {
    __shared__ float tile[64][65];
    int k0 = blockIdx.x * 64;   // DIN/64 = 32
    int n0 = blockIdx.y * 64;   // NCOLS/64 = 96
    int c  = threadIdx.x & 63;
    int r0 = threadIdx.x >> 6;
#pragma unroll
    for (int rr = 0; rr < 16; ++rr) {
        int r = r0 + rr * 4;
        tile[r][c] = W[(size_t)(k0 + r) * NCOLS + n0 + c];
    }
    __syncthreads();
#pragma unroll
    for (int rr = 0; rr < 16; ++rr) {
        int r = r0 + rr * 4;
        int n = n0 + r;
        int nprime = (n % 3) * DD + (n / 3);
        WT[(size_t)nprime * DIN + k0 + c] = f2bf(tile[c][r]);
    }
}

// ---------------- K1: GEMM u = x @ W, epilogue -> u0 (f32), g1,g2 (bf16 sigmoid) ----------------
// A = x_bf16 [MROWS][DIN], Bt = WT_bf16 [NCOLS][DIN]; 128x128 tile, BK=32, 4 waves.
__global__ __launch_bounds__(256) void sru_gemm(const ushort* __restrict__ A,
                                                const ushort* __restrict__ Bt,
                                                const float*  __restrict__ bias,
                                                float*  __restrict__ u0,
                                                ushort* __restrict__ g1,
                                                ushort* __restrict__ g2) {
    __shared__ alignas(16) ushort ldsA[128 * BK];
    __shared__ alignas(16) ushort ldsB[128 * BK];

    int bid = blockIdx.x;                      // 6144 blocks (divisible by 8 -> bijective XCD swizzle)
    int swz = (bid & 7) * 768 + (bid >> 3);
    int bm0 = (swz / 48) * 128;
    int bn0 = (swz % 48) * 128;

    int tid = threadIdx.x;
    int wave = tid >> 6, lane = tid & 63;
    int wm = wave >> 1, wn = wave & 1;

    // staging: thread covers rows (tid>>2) and 64+(tid>>2); LDS linear dest tid*16B.
    // LDS chunk position tid&3 holds source chunk (tid&3) ^ ((row>>1)&3).
    int srow   = tid >> 2;
    int schunk = (tid & 3) ^ ((tid >> 3) & 3);
    const ushort* gA0 = A  + (size_t)(bm0 + srow)      * DIN + schunk * 8;
    const ushort* gA1 = A  + (size_t)(bm0 + 64 + srow) * DIN + schunk * 8;
    const ushort* gB0 = Bt + (size_t)(bn0 + srow)      * DIN + schunk * 8;
    const ushort* gB1 = Bt + (size_t)(bn0 + 64 + srow) * DIN + schunk * 8;
    ushort* lA0 = ldsA + wave * 512;
    ushort* lA1 = ldsA + 2048 + wave * 512;
    ushort* lB0 = ldsB + wave * 512;
    ushort* lB1 = ldsB + 2048 + wave * 512;

    // fragment read offsets (ushort units): row*32 + chunk'*8, chunk' = (lane>>4) ^ ((row>>1)&3)
    int aoff[4], boff[4];
#pragma unroll
    for (int i = 0; i < 4; ++i) {
        int ra = wm * 64 + i * 16 + (lane & 15);
        aoff[i] = ra * BK + (((lane >> 4) ^ ((ra >> 1) & 3)) << 3);
        int rb = wn * 64 + i * 16 + (lane & 15);
        boff[i] = rb * BK + (((lane >> 4) ^ ((rb >> 1) & 3)) << 3);
    }

    f32x4 zero = {0.f, 0.f, 0.f, 0.f};
    f32x4 acc[4][4];
#pragma unroll
    for (int i = 0; i < 4; ++i)
#pragma unroll
        for (int j = 0; j < 4; ++j) acc[i][j] = zero;

    for (int kk = 0; kk < DIN / BK; ++kk) {
        __syncthreads();   // previous compute done before overwrite
        GLOAD16(gA0, lA0); GLOAD16(gA1, lA1);
        GLOAD16(gB0, lB0); GLOAD16(gB1, lB1);
        gA0 += BK; gA1 += BK; gB0 += BK; gB1 += BK;
        __syncthreads();   // compiler drains vmcnt before s_barrier

        short8 af[4], bfr[4];
#pragma unroll
        for (int i = 0; i < 4; ++i) af[i]  = *(const short8*)&ldsA[aoff[i]];
#pragma unroll
        for (int j = 0; j < 4; ++j) bfr[j] = *(const short8*)&ldsB[boff[j]];
#pragma unroll
        for (int i = 0; i < 4; ++i)
#pragma unroll
            for (int j = 0; j < 4; ++j)
                acc[i][j] = __builtin_amdgcn_mfma_f32_16x16x32_bf16(af[i], bfr[j], acc[i][j], 0, 0, 0);
    }

    // epilogue: C row = (lane>>4)*4 + r, col = lane&15 (m89-verified layout)
    int region = bn0 >> 11;  // 0: u0, 1: g1, 2: g2 (BN=128 never straddles 2048-wide regions)
#pragma unroll
    for (int i = 0; i < 4; ++i) {
        int rowb = bm0 + wm * 64 + i * 16 + ((lane >> 4) << 2);
#pragma unroll
        for (int j = 0; j < 4; ++j) {
            int col = bn0 + wn * 64 + j * 16 + (lane & 15);
#pragma unroll
            for (int r = 0; r < 4; ++r) {
                float v = acc[i][j][r];
                size_t oidx = (size_t)(rowb + r) * DD + (col & (DD - 1));
                if (region == 0) {
                    u0[oidx] = v;
                } else {
                    float z = v + bias[col - DD];       // region1: bias[dd]; region2: bias[2048+dd]
                    float g = 1.f / (1.f + __expf(-z));
                    (region == 1 ? g1 : g2)[oidx] = f2bf(g);
                }
            }
        }
    }
}

// ---------------- K2: sequential recurrence over L, one thread per (b,d) chain ----------------
__global__ __launch_bounds__(64) void sru_rec(const float*  __restrict__ u0,
                                              const ushort* __restrict__ g1,
                                              const ushort* __restrict__ g2,
                                              const float*  __restrict__ x,
                                              const float*  __restrict__ c0,
                                              float* __restrict__ h,
                                              float* __restrict__ c_last) {
    int t = blockIdx.x * 64 + threadIdx.x;   // 0..32767 ; t = b*DD + d
    float c = c0[t];
#pragma unroll 8
    for (int l = 0; l < L_SEQ; ++l) {
        int ix = l * (BSZ * DD) + t;         // (l*16+b)*2048 + d
        float uu  = u0[ix];
        float gg1 = bf2f(g1[ix]);
        float gg2 = bf2f(g2[ix]);
        float xx  = x[ix];
        c = (c - uu) * gg1 + uu;
        float e  = __expf(-2.f * fabsf(c));
        float th = (1.f - e) / (1.f + e);
        th = copysignf(th, c);
        h[ix] = (th - xx) * gg2 + xx;
    }
    c_last[t] = c;
}

extern "C" void kernel_launch(void* const* d_in, const int* in_sizes, int n_in,
                              void* d_out, int out_size, void* d_ws, size_t ws_size,
                              hipStream_t stream) {
    const float* x    = (const float*)d_in[0];
    const float* c0   = (const float*)d_in[1];
    const float* W    = (const float*)d_in[2];
    const float* bias = (const float*)d_in[3];
    float* out = (float*)d_out;

    char* ws = (char*)d_ws;
    ushort* xb = (ushort*)(ws);                       //  67,108,864 B  (x bf16)
    ushort* WT = (ushort*)(ws + 67108864);            //  25,165,824 B  (W^T bf16, deinterleaved)
    float*  u0 = (float*) (ws + 92274688);            // 134,217,728 B  (u0 f32)
    ushort* g1 = (ushort*)(ws + 226492416);           //  67,108,864 B  (g1 bf16)
    ushort* g2 = (ushort*)(ws + 293601280);           //  67,108,864 B  -> 360,710,144 total

    hipLaunchKernelGGL(cvt_x_kernel, dim3(2048), dim3(256), 0, stream,
                       (const f32x4*)x, (ushort4v*)xb, MROWS * DIN / 4);
    hipLaunchKernelGGL(transpose_w_kernel, dim3(32, 96), dim3(256), 0, stream, W, WT);
    hipLaunchKernelGGL(sru_gemm, dim3(6144), dim3(256), 0, stream, xb, WT, bias, u0, g1, g2);
    hipLaunchKernelGGL(sru_rec, dim3(512), dim3(64), 0, stream,
                       u0, g1, g2, x, c0, out, out + (size_t)MROWS * DD);
}

// Round 3
// 630.157 us; speedup vs baseline: 1.4620x; 1.4620x over previous
//
#include <hip/hip_runtime.h>
#include <hip/hip_bf16.h>
#include <cstdint>

#define L_SEQ 1024
#define BSZ   16
#define DIN   2048
#define DD    2048
#define MROWS (L_SEQ * BSZ)   // 16384
#define NCOLS (3 * DD)        // 6144
#define BKT   64              // K per tile
#define NT    (DIN / BKT)     // 32 K-tiles

typedef __attribute__((ext_vector_type(8))) short  short8;
typedef __attribute__((ext_vector_type(4))) float  f32x4;
typedef __attribute__((ext_vector_type(4))) ushort ushort4v;

typedef const __attribute__((address_space(1))) void* gas_ptr;
typedef __attribute__((address_space(3))) void*       las_ptr;

#define GLOAD16(g, l) __builtin_amdgcn_global_load_lds((gas_ptr)(g), (las_ptr)(l), 16, 0, 0)

__device__ __forceinline__ float bf2f(ushort u) {
    return __uint_as_float(((uint32_t)u) << 16);
}
__device__ __forceinline__ ushort f2bf(float f) {
    uint32_t u = __float_as_uint(f);
    uint32_t r = u + 0x7FFFu + ((u >> 16) & 1u);  // RNE
    return (ushort)(r >> 16);
}

// ---------------- K0a: x f32 -> bf16 ----------------
__global__ __launch_bounds__(256) void cvt_x_kernel(const f32x4* __restrict__ x,
                                                    ushort4v* __restrict__ xb, int n4) {
    int i = blockIdx.x * blockDim.x + threadIdx.x;
    int stride = gridDim.x * blockDim.x;
    for (; i < n4; i += stride) {
        f32x4 v = x[i];
        ushort4v o;
        o.x = f2bf(v.x); o.y = f2bf(v.y); o.z = f2bf(v.z); o.w = f2bf(v.w);
        xb[i] = o;
    }
}

// ---------------- K0b: W [DIN][NCOLS] f32 -> WT bf16, channel-deinterleaved ----------------
// Source column n -> (dd = n/3, kk = n%3); stored at row n' = kk*DD + dd of WT so GEMM
// output is planar: cols [0,2048)=u0, [2048,4096)=g1, [4096,6144)=g2.
__global__ __launch_bounds__(256) void transpose_w_kernel(const float* __restrict__ W,
                                                          ushort* __restrict__ WT) {
    __shared__ float tile[64][65];
    int k0 = blockIdx.x * 64;
    int n0 = blockIdx.y * 64;
    int c  = threadIdx.x & 63;
    int r0 = threadIdx.x >> 6;
#pragma unroll
    for (int rr = 0; rr < 16; ++rr) {
        int r = r0 + rr * 4;
        tile[r][c] = W[(size_t)(k0 + r) * NCOLS + n0 + c];
    }
    __syncthreads();
#pragma unroll
    for (int rr = 0; rr < 16; ++rr) {
        int r = r0 + rr * 4;
        int n = n0 + r;
        int nprime = (n % 3) * DD + (n / 3);
        WT[(size_t)nprime * DIN + k0 + c] = f2bf(tile[c][r]);
    }
}

// ---------------- K1: 256x256 8-phase GEMM (T2+T3+T4+T5), fused sigmoid epilogue ----------
// A = x_bf16 [MROWS][DIN], Bt = WT_bf16 [NCOLS][DIN]. 512 thr = 8 waves (2M x 4N),
// per-wave output 128x64. LDS 128KiB: 2 dbuf x 4 slots (A0,A1,B0,B1) x 128x64 bf16.
// Slot h of A holds tile rows (wm*128 + h*64 + [0,64)) for wm in {0,1} at slot-row wm*64+r.
// Slot h2 of B holds tile cols (wn*64 + h2*32 + [0,32)) at slot-row wn*32+n.
// XOR swizzle: 16B chunk' = chunk ^ (slot_row & 7); stage uses pre-swizzled global source.
// Schedule per K-tile t (buf cur=t&1): ph0 reads A0+B0, stages A1(t+1)->buf nxt;
// ph1 reads B1, stages B1(t+1)->nxt; ph2 reads A1, stages A0(t+2)->cur;
// ph3 stages B0(t+2)->cur, vmcnt(4) [leaves exactly t+2's A0,B0 in flight].
#define SLOT(b, s) (&lds8[(((b) << 2) + (s)) * 8192])

#define STAGE_A(b, h, kt) do {                                                   \
    const ushort* _g = Ab + (size_t)((h) * 64 + idx) * DIN + (kt) * BKT + akc;   \
    ushort* _l = SLOT(b, (h)) + tid * 8;                                         \
    GLOAD16(_g, _l);                                                             \
    GLOAD16(_g + (size_t)128 * DIN, _l + 4096);                                  \
} while (0)

#define STAGE_B(b, h2, kt) do {                                                  \
    const ushort* _g0 = Bb + (size_t)(brow0 + (h2) * 32) * DIN + (kt) * BKT + akc;\
    const ushort* _g1 = Bb + (size_t)(brow1 + (h2) * 32) * DIN + (kt) * BKT + akc;\
    ushort* _l = SLOT(b, 2 + (h2)) + tid * 8;                                    \
    GLOAD16(_g0, _l);                                                            \
    GLOAD16(_g1, _l + 4096);                                                     \
} while (0)

#define LD_A(b, h) do { const ushort* _s = SLOT(b, (h)) + a_rb;                  \
    _Pragma("unroll") for (int _m = 0; _m < 4; ++_m) {                           \
        aF[_m][0] = *(const short8*)(_s + _m * 1024 + cs0);                      \
        aF[_m][1] = *(const short8*)(_s + _m * 1024 + cs1); }                    \
} while (0)

#define LD_B(b, h2, bF) do { const ushort* _s = SLOT(b, 2 + (h2)) + b_rb;        \
    _Pragma("unroll") for (int _n = 0; _n < 2; ++_n) {                           \
        bF[_n][0] = *(const short8*)(_s + _n * 1024 + cs0);                      \
        bF[_n][1] = *(const short8*)(_s + _n * 1024 + cs1); }                    \
} while (0)

#define MM(mb, bF, nb) do {                                                      \
    __builtin_amdgcn_s_setprio(1);                                               \
    _Pragma("unroll") for (int _m = 0; _m < 4; ++_m)                             \
    _Pragma("unroll") for (int _n = 0; _n < 2; ++_n) {                           \
        acc[(mb)+_m][(nb)+_n] = __builtin_amdgcn_mfma_f32_16x16x32_bf16(         \
            aF[_m][0], bF[_n][0], acc[(mb)+_m][(nb)+_n], 0, 0, 0);               \
        acc[(mb)+_m][(nb)+_n] = __builtin_amdgcn_mfma_f32_16x16x32_bf16(         \
            aF[_m][1], bF[_n][1], acc[(mb)+_m][(nb)+_n], 0, 0, 0); }             \
    __builtin_amdgcn_s_setprio(0);                                               \
    __builtin_amdgcn_sched_barrier(0);                                           \
} while (0)

#define BAR() __builtin_amdgcn_s_barrier()

__global__ __launch_bounds__(512, 2) void sru_gemm8(const ushort* __restrict__ A,
                                                    const ushort* __restrict__ Bt,
                                                    const float*  __restrict__ bias,
                                                    ushort* __restrict__ u0,
                                                    ushort* __restrict__ g1,
                                                    ushort* __restrict__ g2) {
    __shared__ alignas(16) ushort lds8[65536];   // 128 KiB

    int bid = blockIdx.x;                        // 1536 blocks (%8==0 -> bijective swizzle)
    int swz = (bid & 7) * 192 + (bid >> 3);
    int bm0 = (swz / 24) * 256;
    int bn0 = (swz % 24) * 256;

    int tid  = threadIdx.x;
    int wave = tid >> 6, lane = tid & 63;
    int wm = wave >> 2, wn = wave & 3;

    // staging constants (inverse-swizzled source)
    int idx    = tid >> 3;                       // 0..63: slot-row within j-half
    int schunk = (tid & 7) ^ (idx & 7);          // logical 16B chunk for LDS position tid&7
    int akc    = schunk * 8;
    int brow0  = (idx >> 5) * 64 + (idx & 31);
    int brow1  = ((idx >> 5) + 2) * 64 + (idx & 31);
    const ushort* Ab = A  + (size_t)bm0 * DIN;
    const ushort* Bb = Bt + (size_t)bn0 * DIN;

    // fragment-read constants (swizzled ds_read)
    int lrow = lane & 15, lk = lane >> 4, lx = lane & 7;
    int cs0  = ((0 + lk) ^ lx) * 8;              // k-step 0 chunk'
    int cs1  = ((4 + lk) ^ lx) * 8;              // k-step 1 chunk'
    int a_rb = (wm * 64 + lrow) * 64;
    int b_rb = (wn * 32 + lrow) * 64;

    f32x4 acc[8][4];
    f32x4 zero = {0.f, 0.f, 0.f, 0.f};
#pragma unroll
    for (int i = 0; i < 8; ++i)
#pragma unroll
        for (int j = 0; j < 4; ++j) acc[i][j] = zero;

    // prologue: tile0 fully + tile1's A0,B0; wait tile0 landed (outstanding = 4)
    STAGE_A(0, 0, 0); STAGE_A(0, 1, 0); STAGE_B(0, 0, 0); STAGE_B(0, 1, 0);
    STAGE_A(1, 0, 1); STAGE_B(1, 0, 1);
    asm volatile("s_waitcnt vmcnt(4)" ::: "memory");
    BAR();

    short8 aF[4][2], bF0[2][2], bF1[2][2];

    for (int t = 0; t < NT; ++t) {
        int cur = t & 1, nxt = cur ^ 1;
        int kt1 = (t + 1 < NT) ? t + 1 : NT - 1;   // clamped redundant stages are
        int kt2 = (t + 2 < NT) ? t + 2 : NT - 1;   // dead-buffer writes: harmless
        // ph0
        LD_A(cur, 0); LD_B(cur, 0, bF0);
        STAGE_A(nxt, 1, kt1);
        BAR(); MM(0, bF0, 0); BAR();
        // ph1
        LD_B(cur, 1, bF1);
        STAGE_B(nxt, 1, kt1);
        BAR(); MM(0, bF1, 2); BAR();
        // ph2
        LD_A(cur, 1);
        STAGE_A(cur, 0, kt2);
        BAR(); MM(4, bF0, 0); BAR();
        // ph3
        STAGE_B(cur, 0, kt2);
        asm volatile("s_waitcnt vmcnt(4)" ::: "memory");
        BAR(); MM(4, bF1, 2); BAR();
    }
    asm volatile("s_waitcnt vmcnt(0)" ::: "memory");  // drain before epilogue/endpgm

    // epilogue: D row = (lane>>4)*4 + r (A-frag axis), col = lane&15 (B-frag axis)
    int region = bn0 >> 11;                      // 0:u0 1:g1 2:g2 (256 | 2048 -> no straddle)
    int col_l  = (bn0 & (DD - 1)) + wn * 64 + (lane & 15);
#pragma unroll
    for (int mf = 0; mf < 8; ++mf) {
        int rowb = bm0 + wm * 128 + mf * 16 + ((lane >> 4) << 2);
#pragma unroll
        for (int nf = 0; nf < 4; ++nf) {
            int col = col_l + nf * 16;
#pragma unroll
            for (int r = 0; r < 4; ++r) {
                float v = acc[mf][nf][r];
                size_t o = (size_t)(rowb + r) * DD + col;
                if (region == 0) {
                    u0[o] = f2bf(v);
                } else {
                    float z = v + bias[(region - 1) * DD + col];
                    float g = 1.f / (1.f + __expf(-z));
                    (region == 1 ? g1 : g2)[o] = f2bf(g);
                }
            }
        }
    }
}

// ---------------- K2: sequential recurrence over L, one thread per (b,d) chain ----------------
__global__ __launch_bounds__(64) void sru_rec(const ushort* __restrict__ u0,
                                              const ushort* __restrict__ g1,
                                              const ushort* __restrict__ g2,
                                              const float*  __restrict__ x,
                                              const float*  __restrict__ c0,
                                              float* __restrict__ h,
                                              float* __restrict__ c_last) {
    int t = blockIdx.x * 64 + threadIdx.x;   // t = b*DD + d
    float c = c0[t];
#pragma unroll 8
    for (int l = 0; l < L_SEQ; ++l) {
        int ix = l * (BSZ * DD) + t;
        float uu  = bf2f(u0[ix]);
        float gg1 = bf2f(g1[ix]);
        float gg2 = bf2f(g2[ix]);
        float xx  = x[ix];
        c = (c - uu) * gg1 + uu;
        float e  = __expf(-2.f * fabsf(c));
        float th = (1.f - e) / (1.f + e);
        th = copysignf(th, c);
        h[ix] = (th - xx) * gg2 + xx;
    }
    c_last[t] = c;
}

extern "C" void kernel_launch(void* const* d_in, const int* in_sizes, int n_in,
                              void* d_out, int out_size, void* d_ws, size_t ws_size,
                              hipStream_t stream) {
    const float* x    = (const float*)d_in[0];
    const float* c0   = (const float*)d_in[1];
    const float* W    = (const float*)d_in[2];
    const float* bias = (const float*)d_in[3];
    float* out = (float*)d_out;

    char* ws = (char*)d_ws;
    ushort* xb = (ushort*)(ws);                       //  67,108,864 B  (x bf16)
    ushort* WT = (ushort*)(ws + 67108864);            //  25,165,824 B  (W^T bf16, deinterleaved)
    ushort* u0 = (ushort*)(ws + 92274688);            //  67,108,864 B  (u0 bf16)
    ushort* g1 = (ushort*)(ws + 159383552);           //  67,108,864 B
    ushort* g2 = (ushort*)(ws + 226492416);           //  67,108,864 B  -> 293,601,280 total

    hipLaunchKernelGGL(cvt_x_kernel, dim3(2048), dim3(256), 0, stream,
                       (const f32x4*)x, (ushort4v*)xb, MROWS * DIN / 4);
    hipLaunchKernelGGL(transpose_w_kernel, dim3(32, 96), dim3(256), 0, stream, W, WT);
    hipLaunchKernelGGL(sru_gemm8, dim3(1536), dim3(512), 0, stream, xb, WT, bias, u0, g1, g2);
    hipLaunchKernelGGL(sru_rec, dim3(512), dim3(64), 0, stream,
                       u0, g1, g2, x, c0, out, out + (size_t)MROWS * DD);
}

// Round 6
// 583.542 us; speedup vs baseline: 1.5788x; 1.0799x over previous
//
#include <hip/hip_runtime.h>
#include <hip/hip_bf16.h>
#include <cstdint>

#define L_SEQ 1024
#define BSZ   16
#define DIN   2048
#define DD    2048
#define MROWS (L_SEQ * BSZ)   // 16384
#define NCOLS (3 * DD)        // 6144
#define BKT   64              // K per tile
#define NT    (DIN / BKT)     // 32 K-tiles

typedef __attribute__((ext_vector_type(8))) short  short8;
typedef __attribute__((ext_vector_type(4))) float  f32x4;
typedef __attribute__((ext_vector_type(4))) ushort ushort4v;

typedef const __attribute__((address_space(1))) void* gas_ptr;
typedef __attribute__((address_space(3))) void*       las_ptr;

#define GLOAD16(g, l) __builtin_amdgcn_global_load_lds((gas_ptr)(g), (las_ptr)(l), 16, 0, 0)

__device__ __forceinline__ float bf2f(ushort u) {
    return __uint_as_float(((uint32_t)u) << 16);
}
__device__ __forceinline__ ushort f2bf(float f) {
    uint32_t u = __float_as_uint(f);
    uint32_t r = u + 0x7FFFu + ((u >> 16) & 1u);  // RNE
    return (ushort)(r >> 16);
}

// ---------------- K0a: x f32 -> bf16 ----------------
__global__ __launch_bounds__(256) void cvt_x_kernel(const f32x4* __restrict__ x,
                                                    ushort4v* __restrict__ xb, int n4) {
    int i = blockIdx.x * blockDim.x + threadIdx.x;
    int stride = gridDim.x * blockDim.x;
    for (; i < n4; i += stride) {
        f32x4 v = x[i];
        ushort4v o;
        o.x = f2bf(v.x); o.y = f2bf(v.y); o.z = f2bf(v.z); o.w = f2bf(v.w);
        xb[i] = o;
    }
}

// ---------------- K0b: W [DIN][NCOLS] f32 -> WT bf16, channel-deinterleaved ----------------
__global__ __launch_bounds__(256) void transpose_w_kernel(const float* __restrict__ W,
                                                          ushort* __restrict__ WT) {
    __shared__ float tile[64][65];
    int k0 = blockIdx.x * 64;
    int n0 = blockIdx.y * 64;
    int c  = threadIdx.x & 63;
    int r0 = threadIdx.x >> 6;
#pragma unroll
    for (int rr = 0; rr < 16; ++rr) {
        int r = r0 + rr * 4;
        tile[r][c] = W[(size_t)(k0 + r) * NCOLS + n0 + c];
    }
    __syncthreads();
#pragma unroll
    for (int rr = 0; rr < 16; ++rr) {
        int r = r0 + rr * 4;
        int n = n0 + r;
        int nprime = (n % 3) * DD + (n / 3);
        WT[(size_t)nprime * DIN + k0 + c] = f2bf(tile[c][r]);
    }
}

// ---------------- K1: 256x256 8-phase GEMM (Round-3 schedule VERBATIM), swapped-operand
// MFMA + packed epilogue. Slots per buffer: 0=A0 1=A1 2=B0 3=B1 (16KB each).
#define SLOT(b, s) (&lds8[(((b) << 2) + (s)) * 8192])

#define STAGE_A(b, h, kt) do {                                                   \
    const ushort* _g = Ab + (size_t)((h) * 64 + idx) * DIN + (kt) * BKT + akc;   \
    ushort* _l = SLOT(b, (h)) + tid * 8;                                         \
    GLOAD16(_g, _l);                                                             \
    GLOAD16(_g + (size_t)128 * DIN, _l + 4096);                                  \
} while (0)

#define STAGE_B(b, h2, kt) do {                                                  \
    const ushort* _g0 = Bb + (size_t)(brow0 + (h2) * 32) * DIN + (kt) * BKT + akc;\
    const ushort* _g1 = Bb + (size_t)(brow1 + (h2) * 32) * DIN + (kt) * BKT + akc;\
    ushort* _l = SLOT(b, 2 + (h2)) + tid * 8;                                    \
    GLOAD16(_g0, _l);                                                            \
    GLOAD16(_g1, _l + 4096);                                                     \
} while (0)

#define LD_A(b, h) do { const ushort* _s = SLOT(b, (h)) + a_rb;                  \
    _Pragma("unroll") for (int _m = 0; _m < 4; ++_m) {                           \
        aF[_m][0] = *(const short8*)(_s + _m * 1024 + cs0);                      \
        aF[_m][1] = *(const short8*)(_s + _m * 1024 + cs1); }                    \
} while (0)

#define LD_B(b, h2, bF) do { const ushort* _s = SLOT(b, 2 + (h2)) + b_rb;        \
    _Pragma("unroll") for (int _n = 0; _n < 2; ++_n) {                           \
        bF[_n][0] = *(const short8*)(_s + _n * 1024 + cs0);                      \
        bF[_n][1] = *(const short8*)(_s + _n * 1024 + cs1); }                    \
} while (0)

// Swapped operands: D = mfma(b_frag, a_frag, C) -> within-fragment D layout:
// row (m) = lane&15; col (n) quad = (lane>>4)*4 + reg.
#define MM(mb, bF, nb) do {                                                      \
    __builtin_amdgcn_s_setprio(1);                                               \
    _Pragma("unroll") for (int _m = 0; _m < 4; ++_m)                             \
    _Pragma("unroll") for (int _n = 0; _n < 2; ++_n) {                           \
        acc[(mb)+_m][(nb)+_n] = __builtin_amdgcn_mfma_f32_16x16x32_bf16(         \
            bF[_n][0], aF[_m][0], acc[(mb)+_m][(nb)+_n], 0, 0, 0);               \
        acc[(mb)+_m][(nb)+_n] = __builtin_amdgcn_mfma_f32_16x16x32_bf16(         \
            bF[_n][1], aF[_m][1], acc[(mb)+_m][(nb)+_n], 0, 0, 0); }             \
    __builtin_amdgcn_s_setprio(0);                                               \
    __builtin_amdgcn_sched_barrier(0);                                           \
} while (0)

#define BAR() __builtin_amdgcn_s_barrier()

__global__ __launch_bounds__(512, 2) void sru_gemm8(const ushort* __restrict__ A,
                                                    const ushort* __restrict__ Bt,
                                                    const float*  __restrict__ bias,
                                                    ushort* __restrict__ u0,
                                                    ushort* __restrict__ g1,
                                                    ushort* __restrict__ g2) {
    __shared__ alignas(16) ushort lds8[65536];   // 128 KiB

    int bid = blockIdx.x;                        // 1536 blocks (%8==0 -> bijective swizzle)
    int swz = (bid & 7) * 192 + (bid >> 3);
    int bm0 = (swz / 24) * 256;
    int bn0 = (swz % 24) * 256;

    int tid  = threadIdx.x;
    int wave = tid >> 6, lane = tid & 63;
    int wm = wave >> 2, wn = wave & 3;

    // staging constants (inverse-swizzled source)
    int idx    = tid >> 3;
    int schunk = (tid & 7) ^ (idx & 7);
    int akc    = schunk * 8;
    int brow0  = (idx >> 5) * 64 + (idx & 31);
    int brow1  = ((idx >> 5) + 2) * 64 + (idx & 31);
    const ushort* Ab = A  + (size_t)bm0 * DIN;
    const ushort* Bb = Bt + (size_t)bn0 * DIN;

    // fragment-read constants (swizzled ds_read)
    int lrow = lane & 15, lk = lane >> 4, lx = lane & 7;
    int cs0  = ((0 + lk) ^ lx) * 8;
    int cs1  = ((4 + lk) ^ lx) * 8;
    int a_rb = (wm * 64 + lrow) * 64;
    int b_rb = (wn * 32 + lrow) * 64;

    f32x4 acc[8][4];
    f32x4 zero = {0.f, 0.f, 0.f, 0.f};
#pragma unroll
    for (int i = 0; i < 8; ++i)
#pragma unroll
        for (int j = 0; j < 4; ++j) acc[i][j] = zero;

    // prologue: tile0 fully + tile1's A0,B0; wait tile0 landed (outstanding = 4)
    STAGE_A(0, 0, 0); STAGE_A(0, 1, 0); STAGE_B(0, 0, 0); STAGE_B(0, 1, 0);
    STAGE_A(1, 0, 1); STAGE_B(1, 0, 1);
    asm volatile("s_waitcnt vmcnt(4)" ::: "memory");
    BAR();

    short8 aF[4][2], bF0[2][2], bF1[2][2];

    for (int t = 0; t < NT; ++t) {
        int cur = t & 1, nxt = cur ^ 1;
        int kt1 = (t + 1 < NT) ? t + 1 : NT - 1;   // clamped dead stages: harmless
        int kt2 = (t + 2 < NT) ? t + 2 : NT - 1;
        // ph0
        LD_A(cur, 0); LD_B(cur, 0, bF0);
        STAGE_A(nxt, 1, kt1);
        BAR(); MM(0, bF0, 0); BAR();
        // ph1
        LD_B(cur, 1, bF1);
        STAGE_B(nxt, 1, kt1);
        BAR(); MM(0, bF1, 2); BAR();
        // ph2
        LD_A(cur, 1);
        STAGE_A(cur, 0, kt2);
        BAR(); MM(4, bF0, 0); BAR();
        // ph3
        STAGE_B(cur, 0, kt2);
        asm volatile("s_waitcnt vmcnt(4)" ::: "memory");
        BAR(); MM(4, bF1, 2); BAR();
    }
    asm volatile("s_waitcnt vmcnt(0)" ::: "memory");  // drain dead stages

    // epilogue (swapped layout): acc[h*4+_m][j] -> row = bm0 + wm*128 + h*64 + _m*16 + (lane&15),
    // cols = bn0' + wn*64 + j*16 + (lane>>4)*4 + {0..3} -> pack 4 bf16, one 8B store
    int region = bn0 >> 11;                      // 0:u0 1:g1 2:g2
    int colb = (bn0 & (DD - 1)) + wn * 64 + ((lane >> 4) << 2);
    int rowm = bm0 + wm * 128 + (lane & 15);     // FIX: wm*128 (was wm*64)
    if (region == 0) {
#pragma unroll
        for (int j = 0; j < 4; ++j)
#pragma unroll
            for (int i = 0; i < 4; ++i) {
                f32x4 v = acc[i][j];
                uint32_t lo, hi;
                asm("v_cvt_pk_bf16_f32 %0, %1, %2" : "=v"(lo) : "v"(v[0]), "v"(v[1]));
                asm("v_cvt_pk_bf16_f32 %0, %1, %2" : "=v"(hi) : "v"(v[2]), "v"(v[3]));
                uint2 pk; pk.x = lo; pk.y = hi;
                *(uint2*)&u0[(size_t)(rowm + i * 16) * DD + colb + j * 16] = pk;
                f32x4 w = acc[4 + i][j];
                asm("v_cvt_pk_bf16_f32 %0, %1, %2" : "=v"(lo) : "v"(w[0]), "v"(w[1]));
                asm("v_cvt_pk_bf16_f32 %0, %1, %2" : "=v"(hi) : "v"(w[2]), "v"(w[3]));
                pk.x = lo; pk.y = hi;
                *(uint2*)&u0[(size_t)(rowm + 64 + i * 16) * DD + colb + j * 16] = pk;
            }
    } else {
        const float* bp = bias + (size_t)(region - 1) * DD;
        ushort* gp = (region == 1) ? g1 : g2;
#pragma unroll
        for (int j = 0; j < 4; ++j) {
            float4 bv = *(const float4*)&bp[colb + j * 16];
#pragma unroll
            for (int i = 0; i < 8; ++i) {
                f32x4 v = acc[i][j];
                float s0 = 1.f / (1.f + __expf(-(v[0] + bv.x)));
                float s1 = 1.f / (1.f + __expf(-(v[1] + bv.y)));
                float s2 = 1.f / (1.f + __expf(-(v[2] + bv.z)));
                float s3 = 1.f / (1.f + __expf(-(v[3] + bv.w)));
                uint32_t lo, hi;
                asm("v_cvt_pk_bf16_f32 %0, %1, %2" : "=v"(lo) : "v"(s0), "v"(s1));
                asm("v_cvt_pk_bf16_f32 %0, %1, %2" : "=v"(hi) : "v"(s2), "v"(s3));
                uint2 pk; pk.x = lo; pk.y = hi;
                int rr = rowm + (i >> 2) * 64 + (i & 3) * 16;
                *(uint2*)&gp[(size_t)rr * DD + colb + j * 16] = pk;
            }
        }
    }
}

// ---------------- K2: sequential recurrence over L, one thread per (b,d) chain ----------------
__global__ __launch_bounds__(64) void sru_rec(const ushort* __restrict__ u0,
                                              const ushort* __restrict__ g1,
                                              const ushort* __restrict__ g2,
                                              const ushort* __restrict__ xb,
                                              const float*  __restrict__ c0,
                                              float* __restrict__ h,
                                              float* __restrict__ c_last) {
    int t = blockIdx.x * 64 + threadIdx.x;   // t = b*DD + d
    float c = c0[t];
#pragma unroll 8
    for (int l = 0; l < L_SEQ; ++l) {
        int ix = l * (BSZ * DD) + t;
        float uu  = bf2f(u0[ix]);
        float gg1 = bf2f(g1[ix]);
        float gg2 = bf2f(g2[ix]);
        float xx  = bf2f(xb[ix]);
        c = (c - uu) * gg1 + uu;
        float e  = __expf(-2.f * fabsf(c));
        float th = (1.f - e) / (1.f + e);
        th = copysignf(th, c);
        h[ix] = (th - xx) * gg2 + xx;
    }
    c_last[t] = c;
}

extern "C" void kernel_launch(void* const* d_in, const int* in_sizes, int n_in,
                              void* d_out, int out_size, void* d_ws, size_t ws_size,
                              hipStream_t stream) {
    const float* x    = (const float*)d_in[0];
    const float* c0   = (const float*)d_in[1];
    const float* W    = (const float*)d_in[2];
    const float* bias = (const float*)d_in[3];
    float* out = (float*)d_out;

    char* ws = (char*)d_ws;
    ushort* xb = (ushort*)(ws);                       //  67,108,864 B  (x bf16)
    ushort* WT = (ushort*)(ws + 67108864);            //  25,165,824 B  (W^T bf16, deinterleaved)
    ushort* u0 = (ushort*)(ws + 92274688);            //  67,108,864 B  (u0 bf16)
    ushort* g1 = (ushort*)(ws + 159383552);           //  67,108,864 B
    ushort* g2 = (ushort*)(ws + 226492416);           //  67,108,864 B  -> 293,601,280 total

    hipLaunchKernelGGL(cvt_x_kernel, dim3(2048), dim3(256), 0, stream,
                       (const f32x4*)x, (ushort4v*)xb, MROWS * DIN / 4);
    hipLaunchKernelGGL(transpose_w_kernel, dim3(32, 96), dim3(256), 0, stream, W, WT);
    hipLaunchKernelGGL(sru_gemm8, dim3(1536), dim3(512), 0, stream, xb, WT, bias, u0, g1, g2);
    hipLaunchKernelGGL(sru_rec, dim3(512), dim3(64), 0, stream,
                       u0, g1, g2, xb, c0, out, out + (size_t)MROWS * DD);
}

// Round 7
// 576.766 us; speedup vs baseline: 1.5974x; 1.0117x over previous
//
#include <hip/hip_runtime.h>
#include <hip/hip_bf16.h>
#include <cstdint>

#define L_SEQ 1024
#define BSZ   16
#define DIN   2048
#define DD    2048
#define MROWS (L_SEQ * BSZ)   // 16384
#define NCOLS (3 * DD)        // 6144
#define BKT   64              // K per tile
#define NT    (DIN / BKT)     // 32 K-tiles

typedef __attribute__((ext_vector_type(8))) short  short8;
typedef __attribute__((ext_vector_type(4))) float  f32x4;
typedef __attribute__((ext_vector_type(4))) ushort ushort4v;

typedef const __attribute__((address_space(1))) void* gas_ptr;
typedef __attribute__((address_space(3))) void*       las_ptr;

#define GLOAD16(g, l) __builtin_amdgcn_global_load_lds((gas_ptr)(g), (las_ptr)(l), 16, 0, 0)

__device__ __forceinline__ float bf2f(ushort u) {
    return __uint_as_float(((uint32_t)u) << 16);
}
__device__ __forceinline__ ushort f2bf(float f) {
    uint32_t u = __float_as_uint(f);
    uint32_t r = u + 0x7FFFu + ((u >> 16) & 1u);  // RNE
    return (ushort)(r >> 16);
}

// ---------------- K0: fused  x f32->bf16  +  W transpose/deinterleave ----------------
// blocks [0,2048): cvt;  blocks [2048,5120): transpose (32 k-tiles x 96 n-tiles).
// Source col n -> (dd=n/3, kk=n%3) stored at WT row kk*DD+dd so GEMM output is planar.
__global__ __launch_bounds__(256) void pre_kernel(const f32x4* __restrict__ x4,
                                                  ushort4v* __restrict__ xb4,
                                                  const float* __restrict__ W,
                                                  ushort* __restrict__ WT) {
    __shared__ float tile[64][65];
    int bid = blockIdx.x;
    if (bid < 2048) {
        int i = bid * 256 + threadIdx.x;
        const int n4 = MROWS * DIN / 4;
        const int stride = 2048 * 256;
        for (; i < n4; i += stride) {
            f32x4 v = x4[i];
            ushort4v o;
            o.x = f2bf(v.x); o.y = f2bf(v.y); o.z = f2bf(v.z); o.w = f2bf(v.w);
            xb4[i] = o;
        }
    } else {
        int b2 = bid - 2048;
        int k0 = (b2 & 31) * 64;
        int n0 = (b2 >> 5) * 64;
        int c  = threadIdx.x & 63;
        int r0 = threadIdx.x >> 6;
#pragma unroll
        for (int rr = 0; rr < 16; ++rr) {
            int r = r0 + rr * 4;
            tile[r][c] = W[(size_t)(k0 + r) * NCOLS + n0 + c];
        }
        __syncthreads();
#pragma unroll
        for (int rr = 0; rr < 16; ++rr) {
            int r = r0 + rr * 4;
            int n = n0 + r;
            int nprime = (n % 3) * DD + (n / 3);
            WT[(size_t)nprime * DIN + k0 + c] = f2bf(tile[c][r]);
        }
    }
}

// ---------------- K1: 256x256 GEMM, round-6 schedule + FENCED barriers, swapped MFMA ----
// Slots per buffer: 0=A0 1=A1 2=B0 3=B1 (16KB each).
#define SLOT(b, s) (&lds8[(((b) << 2) + (s)) * 8192])

#define STAGE_A(b, h, kt) do {                                                   \
    const ushort* _g = Ab + (size_t)((h) * 64 + idx) * DIN + (kt) * BKT + akc;   \
    ushort* _l = SLOT(b, (h)) + tid * 8;                                         \
    GLOAD16(_g, _l);                                                             \
    GLOAD16(_g + (size_t)128 * DIN, _l + 4096);                                  \
} while (0)

#define STAGE_B(b, h2, kt) do {                                                  \
    const ushort* _g0 = Bb + (size_t)(brow0 + (h2) * 32) * DIN + (kt) * BKT + akc;\
    const ushort* _g1 = Bb + (size_t)(brow1 + (h2) * 32) * DIN + (kt) * BKT + akc;\
    ushort* _l = SLOT(b, 2 + (h2)) + tid * 8;                                    \
    GLOAD16(_g0, _l);                                                            \
    GLOAD16(_g1, _l + 4096);                                                     \
} while (0)

// in-loop pointer-incremented stages (same addresses as STAGE_A/B with kt1=t+1, kt2=t+2)
#define STAGE_A_P(b, h, p) do {                                                  \
    ushort* _l = SLOT(b, (h)) + tid * 8;                                         \
    GLOAD16((p), _l);                                                            \
    GLOAD16((p) + (size_t)128 * DIN, _l + 4096);                                 \
} while (0)

#define STAGE_B_P(b, h2, p0, p1) do {                                            \
    ushort* _l = SLOT(b, 2 + (h2)) + tid * 8;                                    \
    GLOAD16((p0), _l);                                                           \
    GLOAD16((p1), _l + 4096);                                                    \
} while (0)

#define LD_A(b, h) do { const ushort* _s = SLOT(b, (h)) + a_rb;                  \
    _Pragma("unroll") for (int _m = 0; _m < 4; ++_m) {                           \
        aF[_m][0] = *(const short8*)(_s + _m * 1024 + cs0);                      \
        aF[_m][1] = *(const short8*)(_s + _m * 1024 + cs1); }                    \
} while (0)

#define LD_B(b, h2, bF) do { const ushort* _s = SLOT(b, 2 + (h2)) + b_rb;        \
    _Pragma("unroll") for (int _n = 0; _n < 2; ++_n) {                           \
        bF[_n][0] = *(const short8*)(_s + _n * 1024 + cs0);                      \
        bF[_n][1] = *(const short8*)(_s + _n * 1024 + cs1); }                    \
} while (0)

// Swapped operands: D = mfma(b_frag, a_frag, C) -> row (m) = lane&15;
// col (n) quad = (lane>>4)*4 + reg.
#define MM(mb, bF, nb) do {                                                      \
    __builtin_amdgcn_s_setprio(1);                                               \
    _Pragma("unroll") for (int _m = 0; _m < 4; ++_m)                             \
    _Pragma("unroll") for (int _n = 0; _n < 2; ++_n) {                           \
        acc[(mb)+_m][(nb)+_n] = __builtin_amdgcn_mfma_f32_16x16x32_bf16(         \
            bF[_n][0], aF[_m][0], acc[(mb)+_m][(nb)+_n], 0, 0, 0);               \
        acc[(mb)+_m][(nb)+_n] = __builtin_amdgcn_mfma_f32_16x16x32_bf16(         \
            bF[_n][1], aF[_m][1], acc[(mb)+_m][(nb)+_n], 0, 0, 0); }             \
    __builtin_amdgcn_s_setprio(0);                                               \
    __builtin_amdgcn_sched_barrier(0);                                           \
} while (0)

// FENCED barrier: pins LD/STAGE issue into their phase (compiler may not sink
// ds_reads past a raw s_barrier; that sinking serializes LDS latency into the
// MFMA window — the 43.7% vs 62% gap).
#define BARF() do { __builtin_amdgcn_sched_barrier(0);                           \
    __builtin_amdgcn_s_barrier();                                                \
    __builtin_amdgcn_sched_barrier(0); } while (0)

__global__ __launch_bounds__(512, 2) void sru_gemm8(const ushort* __restrict__ A,
                                                    const ushort* __restrict__ Bt,
                                                    const float*  __restrict__ bias,
                                                    ushort* __restrict__ u0,
                                                    ushort* __restrict__ g1,
                                                    ushort* __restrict__ g2) {
    __shared__ alignas(16) ushort lds8[65536];   // 128 KiB

    int bid = blockIdx.x;                        // 1536 blocks (%8==0 -> bijective swizzle)
    int swz = (bid & 7) * 192 + (bid >> 3);
    int bm0 = (swz / 24) * 256;
    int bn0 = (swz % 24) * 256;

    int tid  = threadIdx.x;
    int wave = tid >> 6, lane = tid & 63;
    int wm = wave >> 2, wn = wave & 3;

    // staging constants (inverse-swizzled source)
    int idx    = tid >> 3;
    int schunk = (tid & 7) ^ (idx & 7);
    int akc    = schunk * 8;
    int brow0  = (idx >> 5) * 64 + (idx & 31);
    int brow1  = ((idx >> 5) + 2) * 64 + (idx & 31);
    const ushort* Ab = A  + (size_t)bm0 * DIN;
    const ushort* Bb = Bt + (size_t)bn0 * DIN;

    // in-loop stage pointers (advance BKT per K-tile); unclamped tails are
    // dead-by-schedule and stay inside d_ws (verified: max overrun 256 B into
    // the adjacent ws region, reads only).
    const ushort* pA1  = Ab + (size_t)(64 + idx) * DIN + akc + BKT;       // A1, kt1
    const ushort* pA0  = Ab + (size_t)idx        * DIN + akc + 2 * BKT;   // A0, kt2
    const ushort* pB1a = Bb + (size_t)(brow0 + 32) * DIN + akc + BKT;     // B1, kt1
    const ushort* pB1b = Bb + (size_t)(brow1 + 32) * DIN + akc + BKT;
    const ushort* pB0a = Bb + (size_t)brow0 * DIN + akc + 2 * BKT;        // B0, kt2
    const ushort* pB0b = Bb + (size_t)brow1 * DIN + akc + 2 * BKT;

    // fragment-read constants (swizzled ds_read)
    int lrow = lane & 15, lk = lane >> 4, lx = lane & 7;
    int cs0  = ((0 + lk) ^ lx) * 8;
    int cs1  = ((4 + lk) ^ lx) * 8;
    int a_rb = (wm * 64 + lrow) * 64;
    int b_rb = (wn * 32 + lrow) * 64;

    f32x4 acc[8][4];
    f32x4 zero = {0.f, 0.f, 0.f, 0.f};
#pragma unroll
    for (int i = 0; i < 8; ++i)
#pragma unroll
        for (int j = 0; j < 4; ++j) acc[i][j] = zero;

    // prologue: tile0 fully + tile1's A0,B0; wait tile0 landed (outstanding = 4)
    STAGE_A(0, 0, 0); STAGE_A(0, 1, 0); STAGE_B(0, 0, 0); STAGE_B(0, 1, 0);
    STAGE_A(1, 0, 1); STAGE_B(1, 0, 1);
    asm volatile("s_waitcnt vmcnt(4)" ::: "memory");
    BARF();

    short8 aF[4][2], bF0[2][2], bF1[2][2];

    for (int t = 0; t < NT; ++t) {
        int cur = t & 1, nxt = cur ^ 1;
        // ph0
        LD_A(cur, 0); LD_B(cur, 0, bF0);
        STAGE_A_P(nxt, 1, pA1);
        BARF(); MM(0, bF0, 0); BARF();
        // ph1
        LD_B(cur, 1, bF1);
        STAGE_B_P(nxt, 1, pB1a, pB1b);
        BARF(); MM(0, bF1, 2); BARF();
        // ph2
        LD_A(cur, 1);
        STAGE_A_P(cur, 0, pA0);
        BARF(); MM(4, bF0, 0); BARF();
        // ph3
        STAGE_B_P(cur, 0, pB0a, pB0b);
        asm volatile("s_waitcnt vmcnt(4)" ::: "memory");
        BARF(); MM(4, bF1, 2); BARF();
        pA1 += BKT; pA0 += BKT; pB1a += BKT; pB1b += BKT; pB0a += BKT; pB0b += BKT;
    }
    asm volatile("s_waitcnt vmcnt(0)" ::: "memory");  // drain dead stages

    // epilogue (swapped layout): acc[h*4+i][j] -> row = bm0 + wm*128 + h*64 + i*16 + (lane&15),
    // cols = bn0' + wn*64 + j*16 + (lane>>4)*4 + {0..3} -> pack 4 bf16, one 8B store
    int region = bn0 >> 11;                      // 0:u0 1:g1 2:g2
    int colb = (bn0 & (DD - 1)) + wn * 64 + ((lane >> 4) << 2);
    int rowm = bm0 + wm * 128 + (lane & 15);
    if (region == 0) {
#pragma unroll
        for (int j = 0; j < 4; ++j)
#pragma unroll
            for (int i = 0; i < 4; ++i) {
                f32x4 v = acc[i][j];
                uint32_t lo, hi;
                asm("v_cvt_pk_bf16_f32 %0, %1, %2" : "=v"(lo) : "v"(v[0]), "v"(v[1]));
                asm("v_cvt_pk_bf16_f32 %0, %1, %2" : "=v"(hi) : "v"(v[2]), "v"(v[3]));
                uint2 pk; pk.x = lo; pk.y = hi;
                *(uint2*)&u0[(size_t)(rowm + i * 16) * DD + colb + j * 16] = pk;
                f32x4 w = acc[4 + i][j];
                asm("v_cvt_pk_bf16_f32 %0, %1, %2" : "=v"(lo) : "v"(w[0]), "v"(w[1]));
                asm("v_cvt_pk_bf16_f32 %0, %1, %2" : "=v"(hi) : "v"(w[2]), "v"(w[3]));
                pk.x = lo; pk.y = hi;
                *(uint2*)&u0[(size_t)(rowm + 64 + i * 16) * DD + colb + j * 16] = pk;
            }
    } else {
        const float* bp = bias + (size_t)(region - 1) * DD;
        ushort* gp = (region == 1) ? g1 : g2;
#pragma unroll
        for (int j = 0; j < 4; ++j) {
            float4 bv = *(const float4*)&bp[colb + j * 16];
#pragma unroll
            for (int i = 0; i < 8; ++i) {
                f32x4 v = acc[i][j];
                float s0 = 1.f / (1.f + __expf(-(v[0] + bv.x)));
                float s1 = 1.f / (1.f + __expf(-(v[1] + bv.y)));
                float s2 = 1.f / (1.f + __expf(-(v[2] + bv.z)));
                float s3 = 1.f / (1.f + __expf(-(v[3] + bv.w)));
                uint32_t lo, hi;
                asm("v_cvt_pk_bf16_f32 %0, %1, %2" : "=v"(lo) : "v"(s0), "v"(s1));
                asm("v_cvt_pk_bf16_f32 %0, %1, %2" : "=v"(hi) : "v"(s2), "v"(s3));
                uint2 pk; pk.x = lo; pk.y = hi;
                int rr = rowm + (i >> 2) * 64 + (i & 3) * 16;
                *(uint2*)&gp[(size_t)rr * DD + colb + j * 16] = pk;
            }
        }
    }
}

// ---------------- K2: sequential recurrence over L, one thread per (b,d) chain ----------------
__global__ __launch_bounds__(64) void sru_rec(const ushort* __restrict__ u0,
                                              const ushort* __restrict__ g1,
                                              const ushort* __restrict__ g2,
                                              const ushort* __restrict__ xb,
                                              const float*  __restrict__ c0,
                                              float* __restrict__ h,
                                              float* __restrict__ c_last) {
    int t = blockIdx.x * 64 + threadIdx.x;   // t = b*DD + d
    float c = c0[t];
#pragma unroll 16
    for (int l = 0; l < L_SEQ; ++l) {
        int ix = l * (BSZ * DD) + t;
        float uu  = bf2f(u0[ix]);
        float gg1 = bf2f(g1[ix]);
        float gg2 = bf2f(g2[ix]);
        float xx  = bf2f(xb[ix]);
        c = (c - uu) * gg1 + uu;
        float e  = __expf(-2.f * fabsf(c));
        float th = (1.f - e) / (1.f + e);
        th = copysignf(th, c);
        h[ix] = (th - xx) * gg2 + xx;
    }
    c_last[t] = c;
}

extern "C" void kernel_launch(void* const* d_in, const int* in_sizes, int n_in,
                              void* d_out, int out_size, void* d_ws, size_t ws_size,
                              hipStream_t stream) {
    const float* x    = (const float*)d_in[0];
    const float* c0   = (const float*)d_in[1];
    const float* W    = (const float*)d_in[2];
    const float* bias = (const float*)d_in[3];
    float* out = (float*)d_out;

    char* ws = (char*)d_ws;
    ushort* xb = (ushort*)(ws);                       //  67,108,864 B  (x bf16)
    ushort* WT = (ushort*)(ws + 67108864);            //  25,165,824 B  (W^T bf16, deinterleaved)
    ushort* u0 = (ushort*)(ws + 92274688);            //  67,108,864 B  (u0 bf16)
    ushort* g1 = (ushort*)(ws + 159383552);           //  67,108,864 B
    ushort* g2 = (ushort*)(ws + 226492416);           //  67,108,864 B  -> 293,601,280 total

    hipLaunchKernelGGL(pre_kernel, dim3(5120), dim3(256), 0, stream,
                       (const f32x4*)x, (ushort4v*)xb, W, WT);
    hipLaunchKernelGGL(sru_gemm8, dim3(1536), dim3(512), 0, stream, xb, WT, bias, u0, g1, g2);
    hipLaunchKernelGGL(sru_rec, dim3(512), dim3(64), 0, stream,
                       u0, g1, g2, xb, c0, out, out + (size_t)MROWS * DD);
}

// Round 8
// 572.327 us; speedup vs baseline: 1.6097x; 1.0078x over previous
//
#include <hip/hip_runtime.h>
#include <hip/hip_bf16.h>
#include <cstdint>

#define L_SEQ 1024
#define BSZ   16
#define DIN   2048
#define DD    2048
#define MROWS (L_SEQ * BSZ)   // 16384
#define NCOLS (3 * DD)        // 6144
#define BKT   64              // K per tile
#define NT    (DIN / BKT)     // 32 K-tiles

typedef __attribute__((ext_vector_type(8))) short  short8;
typedef __attribute__((ext_vector_type(4))) float  f32x4;
typedef __attribute__((ext_vector_type(4))) ushort ushort4v;

typedef const __attribute__((address_space(1))) void* gas_ptr;
typedef __attribute__((address_space(3))) void*       las_ptr;

#define GLOAD16(g, l) __builtin_amdgcn_global_load_lds((gas_ptr)(g), (las_ptr)(l), 16, 0, 0)

__device__ __forceinline__ float bf2f(ushort u) {
    return __uint_as_float(((uint32_t)u) << 16);
}
__device__ __forceinline__ ushort f2bf(float f) {
    uint32_t u = __float_as_uint(f);
    uint32_t r = u + 0x7FFFu + ((u >> 16) & 1u);  // RNE
    return (ushort)(r >> 16);
}

// ---------------- K0: fused  x f32->bf16  +  W transpose/deinterleave ----------------
__global__ __launch_bounds__(256) void pre_kernel(const f32x4* __restrict__ x4,
                                                  ushort4v* __restrict__ xb4,
                                                  const float* __restrict__ W,
                                                  ushort* __restrict__ WT) {
    __shared__ float tile[64][65];
    int bid = blockIdx.x;
    if (bid < 2048) {
        int i = bid * 256 + threadIdx.x;
        const int n4 = MROWS * DIN / 4;
        const int stride = 2048 * 256;
        for (; i < n4; i += stride) {
            f32x4 v = x4[i];
            ushort4v o;
            o.x = f2bf(v.x); o.y = f2bf(v.y); o.z = f2bf(v.z); o.w = f2bf(v.w);
            xb4[i] = o;
        }
    } else {
        int b2 = bid - 2048;
        int k0 = (b2 & 31) * 64;
        int n0 = (b2 >> 5) * 64;
        int c  = threadIdx.x & 63;
        int r0 = threadIdx.x >> 6;
#pragma unroll
        for (int rr = 0; rr < 16; ++rr) {
            int r = r0 + rr * 4;
            tile[r][c] = W[(size_t)(k0 + r) * NCOLS + n0 + c];
        }
        __syncthreads();
#pragma unroll
        for (int rr = 0; rr < 16; ++rr) {
            int r = r0 + rr * 4;
            int n = n0 + r;
            int nprime = (n % 3) * DD + (n / 3);
            WT[(size_t)nprime * DIN + k0 + c] = f2bf(tile[c][r]);
        }
    }
}

// ---------------- K1: 256x256 GEMM, round-6 schedule + READ-AHEAD fragments ----------
// Slots per buffer: 0=A0 1=A1 2=B0 3=B1 (16KB each).
// Read-ahead: bF0,bF1 read at ph0 (bF1 used ph1); aFB at ph1 (used ph2/ph3);
// next-tile aFA at ph3 AFTER vmcnt(4)+BAR (proof: tile t+1 fully landed there).
// Stage schedule / vmcnt / barriers / epilogue: identical to round-6 (verified).
#define SLOT(b, s) (&lds8[(((b) << 2) + (s)) * 8192])

#define STAGE_A(b, h, kt) do {                                                   \
    const ushort* _g = Ab + (size_t)((h) * 64 + idx) * DIN + (kt) * BKT + akc;   \
    ushort* _l = SLOT(b, (h)) + tid * 8;                                         \
    GLOAD16(_g, _l);                                                             \
    GLOAD16(_g + (size_t)128 * DIN, _l + 4096);                                  \
} while (0)

#define STAGE_B(b, h2, kt) do {                                                  \
    const ushort* _g0 = Bb + (size_t)(brow0 + (h2) * 32) * DIN + (kt) * BKT + akc;\
    const ushort* _g1 = Bb + (size_t)(brow1 + (h2) * 32) * DIN + (kt) * BKT + akc;\
    ushort* _l = SLOT(b, 2 + (h2)) + tid * 8;                                    \
    GLOAD16(_g0, _l);                                                            \
    GLOAD16(_g1, _l + 4096);                                                     \
} while (0)

#define LD_A2(dst, b, h) do { const ushort* _s = SLOT(b, (h)) + a_rb;            \
    _Pragma("unroll") for (int _m = 0; _m < 4; ++_m) {                           \
        dst[_m][0] = *(const short8*)(_s + _m * 1024 + cs0);                     \
        dst[_m][1] = *(const short8*)(_s + _m * 1024 + cs1); }                   \
} while (0)

#define LD_B(b, h2, bF) do { const ushort* _s = SLOT(b, 2 + (h2)) + b_rb;        \
    _Pragma("unroll") for (int _n = 0; _n < 2; ++_n) {                           \
        bF[_n][0] = *(const short8*)(_s + _n * 1024 + cs0);                      \
        bF[_n][1] = *(const short8*)(_s + _n * 1024 + cs1); }                    \
} while (0)

// Swapped operands: D = mfma(b_frag, a_frag, C) -> row (m) = lane&15;
// col (n) quad = (lane>>4)*4 + reg.
#define MM(mb, aR, bF, nb) do {                                                  \
    __builtin_amdgcn_s_setprio(1);                                               \
    _Pragma("unroll") for (int _m = 0; _m < 4; ++_m)                             \
    _Pragma("unroll") for (int _n = 0; _n < 2; ++_n) {                           \
        acc[(mb)+_m][(nb)+_n] = __builtin_amdgcn_mfma_f32_16x16x32_bf16(         \
            bF[_n][0], aR[_m][0], acc[(mb)+_m][(nb)+_n], 0, 0, 0);               \
        acc[(mb)+_m][(nb)+_n] = __builtin_amdgcn_mfma_f32_16x16x32_bf16(         \
            bF[_n][1], aR[_m][1], acc[(mb)+_m][(nb)+_n], 0, 0, 0); }             \
    __builtin_amdgcn_s_setprio(0);                                               \
    __builtin_amdgcn_sched_barrier(0);                                           \
} while (0)

#define BARF() do { __builtin_amdgcn_sched_barrier(0);                           \
    __builtin_amdgcn_s_barrier();                                                \
    __builtin_amdgcn_sched_barrier(0); } while (0)

__global__ __launch_bounds__(512, 2) void sru_gemm8(const ushort* __restrict__ A,
                                                    const ushort* __restrict__ Bt,
                                                    const float*  __restrict__ bias,
                                                    ushort* __restrict__ u0,
                                                    ushort* __restrict__ g1,
                                                    ushort* __restrict__ g2) {
    __shared__ alignas(16) ushort lds8[65536];   // 128 KiB

    int bid = blockIdx.x;                        // 1536 blocks (%8==0 -> bijective swizzle)
    int swz = (bid & 7) * 192 + (bid >> 3);
    int bm0 = (swz / 24) * 256;
    int bn0 = (swz % 24) * 256;

    int tid  = threadIdx.x;
    int wave = tid >> 6, lane = tid & 63;
    int wm = wave >> 2, wn = wave & 3;

    // staging constants (inverse-swizzled source)
    int idx    = tid >> 3;
    int schunk = (tid & 7) ^ (idx & 7);
    int akc    = schunk * 8;
    int brow0  = (idx >> 5) * 64 + (idx & 31);
    int brow1  = ((idx >> 5) + 2) * 64 + (idx & 31);
    const ushort* Ab = A  + (size_t)bm0 * DIN;
    const ushort* Bb = Bt + (size_t)bn0 * DIN;

    // fragment-read constants (swizzled ds_read)
    int lrow = lane & 15, lk = lane >> 4, lx = lane & 7;
    int cs0  = ((0 + lk) ^ lx) * 8;
    int cs1  = ((4 + lk) ^ lx) * 8;
    int a_rb = (wm * 64 + lrow) * 64;
    int b_rb = (wn * 32 + lrow) * 64;

    f32x4 acc[8][4];
    f32x4 zero = {0.f, 0.f, 0.f, 0.f};
#pragma unroll
    for (int i = 0; i < 8; ++i)
#pragma unroll
        for (int j = 0; j < 4; ++j) acc[i][j] = zero;

    // prologue: tile0 fully + tile1's A0,B0; wait tile0 landed (outstanding = 4);
    // pre-read aFA (= steady-state ph3-end read)
    STAGE_A(0, 0, 0); STAGE_A(0, 1, 0); STAGE_B(0, 0, 0); STAGE_B(0, 1, 0);
    STAGE_A(1, 0, 1); STAGE_B(1, 0, 1);
    asm volatile("s_waitcnt vmcnt(4)" ::: "memory");
    BARF();

    short8 aFA[4][2], aFB[4][2], bF0[2][2], bF1[2][2];
    LD_A2(aFA, 0, 0);
    __builtin_amdgcn_sched_barrier(0);

    for (int t = 0; t < NT; ++t) {
        int cur = t & 1, nxt = cur ^ 1;
        // unclamped t+1/t+2 stages: tail overruns stay inside ws (verified), dead-by-schedule
        // ph0: read bF0 (this phase) + bF1 (ahead, ph1); MM(A0xB0)
        LD_B(cur, 0, bF0);
        LD_B(cur, 1, bF1);
        STAGE_A(nxt, 1, t + 1);
        BARF(); MM(0, aFA, bF0, 0); BARF();
        // ph1: read aFB (ahead, ph2/ph3); MM(A0xB1)
        LD_A2(aFB, cur, 1);
        STAGE_B(nxt, 1, t + 1);
        BARF(); MM(0, aFA, bF1, 2); BARF();
        // ph2: no reads; MM(A1xB0)
        STAGE_A(cur, 0, t + 2);
        BARF(); MM(4, aFB, bF0, 0); BARF();
        // ph3: stage B0(t+2); vmcnt(4) proves tile t+1 landed; read next aFA; MM(A1xB1)
        STAGE_B(cur, 0, t + 2);
        asm volatile("s_waitcnt vmcnt(4)" ::: "memory");
        BARF();
        LD_A2(aFA, nxt, 0);
        MM(4, aFB, bF1, 2);
        BARF();
    }
    asm volatile("s_waitcnt vmcnt(0)" ::: "memory");  // drain dead stages

    // epilogue (swapped layout): acc[h*4+i][j] -> row = bm0 + wm*128 + h*64 + i*16 + (lane&15),
    // cols = bn0' + wn*64 + j*16 + (lane>>4)*4 + {0..3} -> pack 4 bf16, one 8B store
    int region = bn0 >> 11;                      // 0:u0 1:g1 2:g2
    int colb = (bn0 & (DD - 1)) + wn * 64 + ((lane >> 4) << 2);
    int rowm = bm0 + wm * 128 + (lane & 15);
    if (region == 0) {
#pragma unroll
        for (int j = 0; j < 4; ++j)
#pragma unroll
            for (int i = 0; i < 4; ++i) {
                f32x4 v = acc[i][j];
                uint32_t lo, hi;
                asm("v_cvt_pk_bf16_f32 %0, %1, %2" : "=v"(lo) : "v"(v[0]), "v"(v[1]));
                asm("v_cvt_pk_bf16_f32 %0, %1, %2" : "=v"(hi) : "v"(v[2]), "v"(v[3]));
                uint2 pk; pk.x = lo; pk.y = hi;
                *(uint2*)&u0[(size_t)(rowm + i * 16) * DD + colb + j * 16] = pk;
                f32x4 w = acc[4 + i][j];
                asm("v_cvt_pk_bf16_f32 %0, %1, %2" : "=v"(lo) : "v"(w[0]), "v"(w[1]));
                asm("v_cvt_pk_bf16_f32 %0, %1, %2" : "=v"(hi) : "v"(w[2]), "v"(w[3]));
                pk.x = lo; pk.y = hi;
                *(uint2*)&u0[(size_t)(rowm + 64 + i * 16) * DD + colb + j * 16] = pk;
            }
    } else {
        const float* bp = bias + (size_t)(region - 1) * DD;
        ushort* gp = (region == 1) ? g1 : g2;
#pragma unroll
        for (int j = 0; j < 4; ++j) {
            float4 bv = *(const float4*)&bp[colb + j * 16];
#pragma unroll
            for (int i = 0; i < 8; ++i) {
                f32x4 v = acc[i][j];
                float s0 = 1.f / (1.f + __expf(-(v[0] + bv.x)));
                float s1 = 1.f / (1.f + __expf(-(v[1] + bv.y)));
                float s2 = 1.f / (1.f + __expf(-(v[2] + bv.z)));
                float s3 = 1.f / (1.f + __expf(-(v[3] + bv.w)));
                uint32_t lo, hi;
                asm("v_cvt_pk_bf16_f32 %0, %1, %2" : "=v"(lo) : "v"(s0), "v"(s1));
                asm("v_cvt_pk_bf16_f32 %0, %1, %2" : "=v"(hi) : "v"(s2), "v"(s3));
                uint2 pk; pk.x = lo; pk.y = hi;
                int rr = rowm + (i >> 2) * 64 + (i & 3) * 16;
                *(uint2*)&gp[(size_t)rr * DD + colb + j * 16] = pk;
            }
        }
    }
}

// ---------------- K2: sequential recurrence over L, one thread per (b,d) chain ----------------
__global__ __launch_bounds__(64) void sru_rec(const ushort* __restrict__ u0,
                                              const ushort* __restrict__ g1,
                                              const ushort* __restrict__ g2,
                                              const ushort* __restrict__ xb,
                                              const float*  __restrict__ c0,
                                              float* __restrict__ h,
                                              float* __restrict__ c_last) {
    int t = blockIdx.x * 64 + threadIdx.x;   // t = b*DD + d
    float c = c0[t];
#pragma unroll 16
    for (int l = 0; l < L_SEQ; ++l) {
        int ix = l * (BSZ * DD) + t;
        float uu  = bf2f(u0[ix]);
        float gg1 = bf2f(g1[ix]);
        float gg2 = bf2f(g2[ix]);
        float xx  = bf2f(xb[ix]);
        c = (c - uu) * gg1 + uu;
        float e  = __expf(-2.f * fabsf(c));
        float th = (1.f - e) / (1.f + e);
        th = copysignf(th, c);
        h[ix] = (th - xx) * gg2 + xx;
    }
    c_last[t] = c;
}

extern "C" void kernel_launch(void* const* d_in, const int* in_sizes, int n_in,
                              void* d_out, int out_size, void* d_ws, size_t ws_size,
                              hipStream_t stream) {
    const float* x    = (const float*)d_in[0];
    const float* c0   = (const float*)d_in[1];
    const float* W    = (const float*)d_in[2];
    const float* bias = (const float*)d_in[3];
    float* out = (float*)d_out;

    char* ws = (char*)d_ws;
    ushort* xb = (ushort*)(ws);                       //  67,108,864 B  (x bf16)
    ushort* WT = (ushort*)(ws + 67108864);            //  25,165,824 B  (W^T bf16, deinterleaved)
    ushort* u0 = (ushort*)(ws + 92274688);            //  67,108,864 B  (u0 bf16)
    ushort* g1 = (ushort*)(ws + 159383552);           //  67,108,864 B
    ushort* g2 = (ushort*)(ws + 226492416);           //  67,108,864 B  -> 293,601,280 total

    hipLaunchKernelGGL(pre_kernel, dim3(5120), dim3(256), 0, stream,
                       (const f32x4*)x, (ushort4v*)xb, W, WT);
    hipLaunchKernelGGL(sru_gemm8, dim3(1536), dim3(512), 0, stream, xb, WT, bias, u0, g1, g2);
    hipLaunchKernelGGL(sru_rec, dim3(512), dim3(64), 0, stream,
                       u0, g1, g2, xb, c0, out, out + (size_t)MROWS * DD);
}